// Round 6
// baseline (244.899 us; speedup 1.0000x reference)
//
#include <hip/hip_runtime.h>
#include <math.h>

#define NPTS 6890
#define BATCH 1024
#define FLOATS_PER_BATCH (NPTS * 3)   // 20670; mod 4 == 2
#define NGROUPS 1722                  // groups of 4 points in the aligned region
#define NT 512                        // threads per block (8 waves)

// Native 4-float vector: __builtin_nontemporal_load/store accepts these
// (it rejects HIP_vector_type<float,4>). Same 16B size/alignment as float4.
typedef float f4 __attribute__((ext_vector_type(4)));

// ---------------------------------------------------------------------------
// Fully fused kernel (R3 structure), with NON-TEMPORAL loads/stores.
// The stream is touch-once (fusion removed all reuse), and the 233 MB
// working set straddles the 256 MB L3 -> persistent half-hit thrash capped
// at ~2.25 TB/s delivered (R0-R3 evidence). nt accesses bypass the cache
// path; prediction is the HBM streaming ceiling (~6.3 TB/s) applies.
//   Phase 1: load batch into registers, accumulate 16 Procrustes sums.
//   Phase 2: block-reduce; lane 0 runs fp64 solve (register-resident).
//   Phase 3: apply |scale*R*p + t - g| from registers, nt-store.
// Batch base b*20670 is 16B-aligned only for even b; odd b skips 2 points
// (6 floats) to realign. Leftover 2 points handled scalar by threads 0/1.
// ---------------------------------------------------------------------------

__device__ __forceinline__ void accum(float* acc, float p0, float p1, float p2,
                                      float g0, float g1, float g2) {
  acc[0] += p0;  acc[1] += p1;  acc[2] += p2;
  acc[3] += g0;  acc[4] += g1;  acc[5] += g2;
  acc[6] += p0 * p0 + p1 * p1 + p2 * p2;
  acc[7]  += p0 * g0;  acc[8]  += p0 * g1;  acc[9]  += p0 * g2;
  acc[10] += p1 * g0;  acc[11] += p1 * g1;  acc[12] += p1 * g2;
  acc[13] += p2 * g0;  acc[14] += p2 * g1;  acc[15] += p2 * g2;
}

__device__ __forceinline__ void accum_group(float* acc,
                                            const f4& a0, const f4& a1,
                                            const f4& a2, const f4& e0,
                                            const f4& e1, const f4& e2) {
  accum(acc, a0.x, a0.y, a0.z, e0.x, e0.y, e0.z);
  accum(acc, a0.w, a1.x, a1.y, e0.w, e1.x, e1.y);
  accum(acc, a1.z, a1.w, a2.x, e1.z, e1.w, e2.x);
  accum(acc, a2.y, a2.z, a2.w, e2.y, e2.z, e2.w);
}

struct F3 { float x, y, z; };

__device__ __forceinline__ F3 xform(const float* m, float p0, float p1,
                                    float p2, float g0, float g1, float g2) {
  F3 o;
  o.x = fabsf(m[0] * p0 + m[1] * p1 + m[2] * p2 + m[9] - g0);
  o.y = fabsf(m[3] * p0 + m[4] * p1 + m[5] * p2 + m[10] - g1);
  o.z = fabsf(m[6] * p0 + m[7] * p1 + m[8] * p2 + m[11] - g2);
  return o;
}

// Transform 4 points of one group; results assembled into 3 f4s via scalars.
__device__ __forceinline__ void apply_group(const float* m,
                                            const f4& a0, const f4& a1,
                                            const f4& a2, const f4& e0,
                                            const f4& e1, const f4& e2,
                                            f4& r0, f4& r1, f4& r2) {
  const F3 u = xform(m, a0.x, a0.y, a0.z, e0.x, e0.y, e0.z);
  const F3 v = xform(m, a0.w, a1.x, a1.y, e0.w, e1.x, e1.y);
  const F3 w = xform(m, a1.z, a1.w, a2.x, e1.z, e1.w, e2.x);
  const F3 q = xform(m, a2.y, a2.z, a2.w, e2.y, e2.z, e2.w);
  r0 = (f4){u.x, u.y, u.z, v.x};
  r1 = (f4){v.y, v.z, w.x, w.y};
  r2 = (f4){w.z, q.x, q.y, q.z};
}

// One Jacobi rotation (p,q) with constant indices (fully register-resident).
#define JROT(p, q, r)                                                         \
  do {                                                                        \
    const double apq = A[p][q];                                               \
    if (apq != 0.0) {                                                         \
      const double theta = (A[q][q] - A[p][p]) / (2.0 * apq);                 \
      const double tt = ((theta >= 0.0) ? 1.0 : -1.0) /                       \
                        (fabs(theta) + sqrt(theta * theta + 1.0));            \
      const double cc = 1.0 / sqrt(tt * tt + 1.0);                            \
      const double sn = tt * cc;                                              \
      const double app = A[p][p], aqq = A[q][q];                              \
      A[p][p] = app - tt * apq;                                               \
      A[q][q] = aqq + tt * apq;                                               \
      A[p][q] = 0.0; A[q][p] = 0.0;                                          \
      const double arp = A[r][p], arq = A[r][q];                              \
      A[r][p] = cc * arp - sn * arq; A[p][r] = A[r][p];                       \
      A[r][q] = sn * arp + cc * arq; A[q][r] = A[r][q];                       \
      _Pragma("unroll")                                                       \
      for (int k = 0; k < 3; ++k) {                                           \
        const double vkp = V[k][p], vkq = V[k][q];                            \
        V[k][p] = cc * vkp - sn * vkq;                                        \
        V[k][q] = sn * vkp + cc * vkq;                                        \
      }                                                                       \
    }                                                                         \
  } while (0)

__global__ __launch_bounds__(NT, 2) void fused_kernel(
    const float* __restrict__ pred, const float* __restrict__ gt,
    float* __restrict__ out) {
  const int b = blockIdx.x;
  const int t = (int)threadIdx.x;
  const size_t ofs0 = (size_t)b * FLOATS_PER_BATCH;
  const int skip = (b & 1) ? 2 : 0;                  // points skipped at head
  const size_t ofs = ofs0 + (size_t)skip * 3;        // 16B-aligned float idx
  const f4* __restrict__ P = (const f4*)(pred + ofs);
  const f4* __restrict__ G = (const f4*)(gt + ofs);
  f4* __restrict__ O = (f4*)(out + ofs);

  __shared__ float red[8][16][17];   // cross-wave partials (+1 pad)
  __shared__ float sums_lds[16];
  __shared__ float pm[12];

  // ---- Phase 1: nt-load whole batch into registers, accumulate 16 sums ----
  f4 rp[4][3], rg[4][3];
  const bool has3 = (t < NGROUPS - 3 * NT);          // t < 186
#pragma unroll
  for (int k = 0; k < 3; ++k) {
    const int g = t + NT * k;                        // always < 1536 <= NGROUPS
    rp[k][0] = __builtin_nontemporal_load(&P[3 * g]);
    rp[k][1] = __builtin_nontemporal_load(&P[3 * g + 1]);
    rp[k][2] = __builtin_nontemporal_load(&P[3 * g + 2]);
    rg[k][0] = __builtin_nontemporal_load(&G[3 * g]);
    rg[k][1] = __builtin_nontemporal_load(&G[3 * g + 1]);
    rg[k][2] = __builtin_nontemporal_load(&G[3 * g + 2]);
  }
  if (has3) {
    const int g = t + NT * 3;                        // 1536 + t < 1722
    rp[3][0] = __builtin_nontemporal_load(&P[3 * g]);
    rp[3][1] = __builtin_nontemporal_load(&P[3 * g + 1]);
    rp[3][2] = __builtin_nontemporal_load(&P[3 * g + 2]);
    rg[3][0] = __builtin_nontemporal_load(&G[3 * g]);
    rg[3][1] = __builtin_nontemporal_load(&G[3 * g + 1]);
    rg[3][2] = __builtin_nontemporal_load(&G[3 * g + 2]);
  } else {
    // keep registers defined (not strictly needed, avoids UB warnings)
#pragma unroll
    for (int j = 0; j < 3; ++j) { rp[3][j] = (f4)(0.f); rg[3][j] = (f4)(0.f); }
  }
  // leftover 2 points per batch (head for odd b, tail for even b)
  float lp0 = 0.f, lp1 = 0.f, lp2 = 0.f, lg0 = 0.f, lg1 = 0.f, lg2 = 0.f;
  const bool hasL = (t < 2);
  if (hasL) {
    const int n = skip ? t : (NPTS - 2 + t);
    const float* pp = pred + ofs0 + 3 * n;
    const float* gg = gt + ofs0 + 3 * n;
    lp0 = pp[0]; lp1 = pp[1]; lp2 = pp[2];
    lg0 = gg[0]; lg1 = gg[1]; lg2 = gg[2];
  }

  float acc[16];
#pragma unroll
  for (int i = 0; i < 16; ++i) acc[i] = 0.f;
#pragma unroll
  for (int k = 0; k < 3; ++k)
    accum_group(acc, rp[k][0], rp[k][1], rp[k][2], rg[k][0], rg[k][1], rg[k][2]);
  if (has3)
    accum_group(acc, rp[3][0], rp[3][1], rp[3][2], rg[3][0], rg[3][1], rg[3][2]);
  if (hasL) accum(acc, lp0, lp1, lp2, lg0, lg1, lg2);

  // ---- Phase 2: block reduction + single-lane fp64 solve ----
#pragma unroll
  for (int i = 0; i < 16; ++i) {
    acc[i] += __shfl_xor(acc[i], 16, 64);
    acc[i] += __shfl_xor(acc[i], 32, 64);
  }
  const int wave = t >> 6;
  const int lane = t & 63;
  if (lane < 16) {
#pragma unroll
    for (int i = 0; i < 16; ++i) red[wave][lane][i] = acc[i];
  }
  __syncthreads();
  if (t < 16) {
    float s = 0.f;
#pragma unroll
    for (int w = 0; w < 8; ++w)
#pragma unroll
      for (int r = 0; r < 16; ++r) s += red[w][r][t];
    sums_lds[t] = s;
  }
  __syncthreads();

  if (t == 0) {
    double s[16];
#pragma unroll
    for (int i = 0; i < 16; ++i) s[i] = (double)sums_lds[i];
    const double Ninv = 1.0 / (double)NPTS;
    double sp[3] = {s[0], s[1], s[2]};
    double sg[3] = {s[3], s[4], s[5]};
    double mu1[3], mu2[3];
#pragma unroll
    for (int i = 0; i < 3; ++i) { mu1[i] = sp[i] * Ninv; mu2[i] = sg[i] * Ninv; }
    const double var1 =
        s[6] - (sp[0] * sp[0] + sp[1] * sp[1] + sp[2] * sp[2]) * Ninv;

    double K[3][3];
#pragma unroll
    for (int i = 0; i < 3; ++i)
#pragma unroll
      for (int j = 0; j < 3; ++j)
        K[i][j] = s[7 + 3 * i + j] - sp[i] * sg[j] * Ninv + 1e-8;

    double A[3][3];
#pragma unroll
    for (int i = 0; i < 3; ++i)
#pragma unroll
      for (int j = 0; j < 3; ++j)
        A[i][j] = K[0][i] * K[0][j] + K[1][i] * K[1][j] + K[2][i] * K[2][j];

    double V[3][3] = {{1, 0, 0}, {0, 1, 0}, {0, 0, 1}};
    for (int sweep = 0; sweep < 30; ++sweep) {
      const double off =
          A[0][1] * A[0][1] + A[0][2] * A[0][2] + A[1][2] * A[1][2];
      const double nrm = A[0][0] + A[1][1] + A[2][2];
      if (off <= 1e-30 * nrm * nrm) break;
      JROT(0, 1, 2);
      JROT(0, 2, 1);
      JROT(1, 2, 0);
    }

    // sort eigenvalues descending, carrying V columns (constant indices only)
    double wv[3] = {A[0][0], A[1][1], A[2][2]};
    if (wv[0] < wv[1]) {
      double tw = wv[0]; wv[0] = wv[1]; wv[1] = tw;
#pragma unroll
      for (int k = 0; k < 3; ++k) {
        double tv = V[k][0]; V[k][0] = V[k][1]; V[k][1] = tv;
      }
    }
    if (wv[0] < wv[2]) {
      double tw = wv[0]; wv[0] = wv[2]; wv[2] = tw;
#pragma unroll
      for (int k = 0; k < 3; ++k) {
        double tv = V[k][0]; V[k][0] = V[k][2]; V[k][2] = tv;
      }
    }
    if (wv[1] < wv[2]) {
      double tw = wv[1]; wv[1] = wv[2]; wv[2] = tw;
#pragma unroll
      for (int k = 0; k < 3; ++k) {
        double tv = V[k][1]; V[k][1] = V[k][2]; V[k][2] = tv;
      }
    }
    const double sv0 = sqrt(fmax(wv[0], 0.0));
    const double sv1 = sqrt(fmax(wv[1], 0.0));
    const double sv2 = sqrt(fmax(wv[2], 0.0));

    const double detK =
        K[0][0] * (K[1][1] * K[2][2] - K[1][2] * K[2][1]) -
        K[0][1] * (K[1][0] * K[2][2] - K[1][2] * K[2][0]) +
        K[0][2] * (K[1][0] * K[2][1] - K[1][1] * K[2][0]);
    const double sgn = (detK > 0.0) ? 1.0 : ((detK < 0.0) ? -1.0 : 0.0);

    const double floor0 = sv0 * 1e-12 + 1e-300;
    const double z0 = 1.0 / fmax(sv0, floor0);
    const double z1 = 1.0 / fmax(sv1, floor0);
    const double z2 = sgn / fmax(sv2, floor0);

    double W[3][3];
#pragma unroll
    for (int a = 0; a < 3; ++a)
#pragma unroll
      for (int c = 0; c < 3; ++c)
        W[a][c] = V[a][0] * V[c][0] * z0 + V[a][1] * V[c][1] * z1 +
                  V[a][2] * V[c][2] * z2;

    double R[3][3];
#pragma unroll
    for (int a = 0; a < 3; ++a)
#pragma unroll
      for (int c = 0; c < 3; ++c)
        R[a][c] = W[a][0] * K[c][0] + W[a][1] * K[c][1] + W[a][2] * K[c][2];

    const double trace = sv0 + sv1 + sgn * sv2;
    const double scale = trace / var1;

#pragma unroll
    for (int a = 0; a < 3; ++a) {
#pragma unroll
      for (int c = 0; c < 3; ++c) pm[3 * a + c] = (float)(scale * R[a][c]);
      pm[9 + a] = (float)(mu2[a] - scale * (R[a][0] * mu1[0] +
                                            R[a][1] * mu1[1] +
                                            R[a][2] * mu1[2]));
    }
  }
  __syncthreads();

  // ---- Phase 3: apply from register-held data, nt-store ----
  float m[12];
#pragma unroll
  for (int i = 0; i < 12; ++i) m[i] = pm[i];

#pragma unroll
  for (int k = 0; k < 3; ++k) {
    const int g = t + NT * k;
    f4 r0, r1, r2;
    apply_group(m, rp[k][0], rp[k][1], rp[k][2], rg[k][0], rg[k][1], rg[k][2],
                r0, r1, r2);
    __builtin_nontemporal_store(r0, &O[3 * g]);
    __builtin_nontemporal_store(r1, &O[3 * g + 1]);
    __builtin_nontemporal_store(r2, &O[3 * g + 2]);
  }
  if (has3) {
    const int g = t + NT * 3;
    f4 r0, r1, r2;
    apply_group(m, rp[3][0], rp[3][1], rp[3][2], rg[3][0], rg[3][1], rg[3][2],
                r0, r1, r2);
    __builtin_nontemporal_store(r0, &O[3 * g]);
    __builtin_nontemporal_store(r1, &O[3 * g + 1]);
    __builtin_nontemporal_store(r2, &O[3 * g + 2]);
  }
  if (hasL) {
    const int n = skip ? t : (NPTS - 2 + t);
    float* oo = out + ofs0 + 3 * n;
    const F3 r = xform(m, lp0, lp1, lp2, lg0, lg1, lg2);
    oo[0] = r.x; oo[1] = r.y; oo[2] = r.z;
  }
}

extern "C" void kernel_launch(void* const* d_in, const int* in_sizes, int n_in,
                              void* d_out, int out_size, void* d_ws, size_t ws_size,
                              hipStream_t stream) {
  const float* pred = (const float*)d_in[0];
  const float* gt   = (const float*)d_in[1];
  float* out = (float*)d_out;
  hipLaunchKernelGGL(fused_kernel, dim3(BATCH), dim3(NT), 0, stream,
                     pred, gt, out);
}

// Round 7
// 228.708 us; speedup vs baseline: 1.0708x; 1.0708x over previous
//
#include <hip/hip_runtime.h>
#include <math.h>

#define NPTS 6890
#define BATCH 1024
#define FLOATS_PER_BATCH (NPTS * 3)   // 20670; mod 4 == 2
#define NGROUPS 1722                  // groups of 4 points in the aligned region
#define NT 512                        // threads per block (8 waves)
#define CHUNK_F4 (3 * NT)             // 1536 f4s staged per store chunk (24 KB)

// Native 4-float vector: __builtin_nontemporal_store accepts these
// (it rejects HIP_vector_type<float,4>). Same 16B size/alignment as float4.
typedef float f4 __attribute__((ext_vector_type(4)));

// ---------------------------------------------------------------------------
// Fully fused kernel. KEY CHANGE vs R6: loads are TEMPORAL (L3 retains the
// 169 MB of inputs across iterations; 169 < 256 MB L3), stores are
// NON-TEMPORAL and made CONTIGUOUS via LDS staging (out is dead-after-write;
// streaming it to HBM keeps it from thrashing the L3, and contiguity kills
// the 1.4x partial-line write amplification R6 measured).
//   Phase 1: load batch into registers, accumulate 16 Procrustes sums.
//   Phase 2: block-reduce; lane 0 runs fp64 solve (register-resident).
//   Phase 3: apply |scale*R*p + t - g|; stage 24KB chunks in LDS; nt-store
//            linearly (1KB contiguous per wave-instruction).
// Batch base b*20670 is 16B-aligned only for even b; odd b skips 2 points
// (6 floats) to realign. Leftover 2 points handled scalar by threads 0/1.
// ---------------------------------------------------------------------------

__device__ __forceinline__ void accum(float* acc, float p0, float p1, float p2,
                                      float g0, float g1, float g2) {
  acc[0] += p0;  acc[1] += p1;  acc[2] += p2;
  acc[3] += g0;  acc[4] += g1;  acc[5] += g2;
  acc[6] += p0 * p0 + p1 * p1 + p2 * p2;
  acc[7]  += p0 * g0;  acc[8]  += p0 * g1;  acc[9]  += p0 * g2;
  acc[10] += p1 * g0;  acc[11] += p1 * g1;  acc[12] += p1 * g2;
  acc[13] += p2 * g0;  acc[14] += p2 * g1;  acc[15] += p2 * g2;
}

__device__ __forceinline__ void accum_group(float* acc,
                                            const f4& a0, const f4& a1,
                                            const f4& a2, const f4& e0,
                                            const f4& e1, const f4& e2) {
  accum(acc, a0.x, a0.y, a0.z, e0.x, e0.y, e0.z);
  accum(acc, a0.w, a1.x, a1.y, e0.w, e1.x, e1.y);
  accum(acc, a1.z, a1.w, a2.x, e1.z, e1.w, e2.x);
  accum(acc, a2.y, a2.z, a2.w, e2.y, e2.z, e2.w);
}

struct F3 { float x, y, z; };

__device__ __forceinline__ F3 xform(const float* m, float p0, float p1,
                                    float p2, float g0, float g1, float g2) {
  F3 o;
  o.x = fabsf(m[0] * p0 + m[1] * p1 + m[2] * p2 + m[9] - g0);
  o.y = fabsf(m[3] * p0 + m[4] * p1 + m[5] * p2 + m[10] - g1);
  o.z = fabsf(m[6] * p0 + m[7] * p1 + m[8] * p2 + m[11] - g2);
  return o;
}

// Transform 4 points of one group; results assembled into 3 f4s via scalars.
__device__ __forceinline__ void apply_group(const float* m,
                                            const f4& a0, const f4& a1,
                                            const f4& a2, const f4& e0,
                                            const f4& e1, const f4& e2,
                                            f4& r0, f4& r1, f4& r2) {
  const F3 u = xform(m, a0.x, a0.y, a0.z, e0.x, e0.y, e0.z);
  const F3 v = xform(m, a0.w, a1.x, a1.y, e0.w, e1.x, e1.y);
  const F3 w = xform(m, a1.z, a1.w, a2.x, e1.z, e1.w, e2.x);
  const F3 q = xform(m, a2.y, a2.z, a2.w, e2.y, e2.z, e2.w);
  r0 = (f4){u.x, u.y, u.z, v.x};
  r1 = (f4){v.y, v.z, w.x, w.y};
  r2 = (f4){w.z, q.x, q.y, q.z};
}

// One Jacobi rotation (p,q) with constant indices (fully register-resident).
#define JROT(p, q, r)                                                         \
  do {                                                                        \
    const double apq = A[p][q];                                               \
    if (apq != 0.0) {                                                         \
      const double theta = (A[q][q] - A[p][p]) / (2.0 * apq);                 \
      const double tt = ((theta >= 0.0) ? 1.0 : -1.0) /                       \
                        (fabs(theta) + sqrt(theta * theta + 1.0));            \
      const double cc = 1.0 / sqrt(tt * tt + 1.0);                            \
      const double sn = tt * cc;                                              \
      const double app = A[p][p], aqq = A[q][q];                              \
      A[p][p] = app - tt * apq;                                               \
      A[q][q] = aqq + tt * apq;                                               \
      A[p][q] = 0.0; A[q][p] = 0.0;                                          \
      const double arp = A[r][p], arq = A[r][q];                              \
      A[r][p] = cc * arp - sn * arq; A[p][r] = A[r][p];                       \
      A[r][q] = sn * arp + cc * arq; A[q][r] = A[r][q];                       \
      _Pragma("unroll")                                                       \
      for (int k = 0; k < 3; ++k) {                                           \
        const double vkp = V[k][p], vkq = V[k][q];                            \
        V[k][p] = cc * vkp - sn * vkq;                                        \
        V[k][q] = sn * vkp + cc * vkq;                                        \
      }                                                                       \
    }                                                                         \
  } while (0)

__global__ __launch_bounds__(NT, 2) void fused_kernel(
    const float* __restrict__ pred, const float* __restrict__ gt,
    float* __restrict__ out) {
  const int b = blockIdx.x;
  const int t = (int)threadIdx.x;
  const size_t ofs0 = (size_t)b * FLOATS_PER_BATCH;
  const int skip = (b & 1) ? 2 : 0;                  // points skipped at head
  const size_t ofs = ofs0 + (size_t)skip * 3;        // 16B-aligned float idx
  const f4* __restrict__ P = (const f4*)(pred + ofs);
  const f4* __restrict__ G = (const f4*)(gt + ofs);
  f4* __restrict__ O = (f4*)(out + ofs);

  __shared__ float red[8][16][17];   // cross-wave partials (+1 pad)
  __shared__ float sums_lds[16];
  __shared__ float pm[12];
  __shared__ f4 stage[CHUNK_F4];     // 24 KB output staging (contiguous nt-store)

  // ---- Phase 1: temporal-load whole batch into registers, accumulate ----
  f4 rp[4][3], rg[4][3];
  const bool has3 = (t < NGROUPS - 3 * NT);          // t < 186
#pragma unroll
  for (int k = 0; k < 3; ++k) {
    const int g = t + NT * k;                        // always < 1536 <= NGROUPS
    rp[k][0] = P[3 * g]; rp[k][1] = P[3 * g + 1]; rp[k][2] = P[3 * g + 2];
    rg[k][0] = G[3 * g]; rg[k][1] = G[3 * g + 1]; rg[k][2] = G[3 * g + 2];
  }
  if (has3) {
    const int g = t + NT * 3;                        // 1536 + t < 1722
    rp[3][0] = P[3 * g]; rp[3][1] = P[3 * g + 1]; rp[3][2] = P[3 * g + 2];
    rg[3][0] = G[3 * g]; rg[3][1] = G[3 * g + 1]; rg[3][2] = G[3 * g + 2];
  } else {
#pragma unroll
    for (int j = 0; j < 3; ++j) { rp[3][j] = (f4)(0.f); rg[3][j] = (f4)(0.f); }
  }
  // leftover 2 points per batch (head for odd b, tail for even b)
  float lp0 = 0.f, lp1 = 0.f, lp2 = 0.f, lg0 = 0.f, lg1 = 0.f, lg2 = 0.f;
  const bool hasL = (t < 2);
  if (hasL) {
    const int n = skip ? t : (NPTS - 2 + t);
    const float* pp = pred + ofs0 + 3 * n;
    const float* gg = gt + ofs0 + 3 * n;
    lp0 = pp[0]; lp1 = pp[1]; lp2 = pp[2];
    lg0 = gg[0]; lg1 = gg[1]; lg2 = gg[2];
  }

  float acc[16];
#pragma unroll
  for (int i = 0; i < 16; ++i) acc[i] = 0.f;
#pragma unroll
  for (int k = 0; k < 3; ++k)
    accum_group(acc, rp[k][0], rp[k][1], rp[k][2], rg[k][0], rg[k][1], rg[k][2]);
  if (has3)
    accum_group(acc, rp[3][0], rp[3][1], rp[3][2], rg[3][0], rg[3][1], rg[3][2]);
  if (hasL) accum(acc, lp0, lp1, lp2, lg0, lg1, lg2);

  // ---- Phase 2: block reduction + single-lane fp64 solve ----
#pragma unroll
  for (int i = 0; i < 16; ++i) {
    acc[i] += __shfl_xor(acc[i], 16, 64);
    acc[i] += __shfl_xor(acc[i], 32, 64);
  }
  const int wave = t >> 6;
  const int lane = t & 63;
  if (lane < 16) {
#pragma unroll
    for (int i = 0; i < 16; ++i) red[wave][lane][i] = acc[i];
  }
  __syncthreads();
  if (t < 16) {
    float s = 0.f;
#pragma unroll
    for (int w = 0; w < 8; ++w)
#pragma unroll
      for (int r = 0; r < 16; ++r) s += red[w][r][t];
    sums_lds[t] = s;
  }
  __syncthreads();

  if (t == 0) {
    double s[16];
#pragma unroll
    for (int i = 0; i < 16; ++i) s[i] = (double)sums_lds[i];
    const double Ninv = 1.0 / (double)NPTS;
    double sp[3] = {s[0], s[1], s[2]};
    double sg[3] = {s[3], s[4], s[5]};
    double mu1[3], mu2[3];
#pragma unroll
    for (int i = 0; i < 3; ++i) { mu1[i] = sp[i] * Ninv; mu2[i] = sg[i] * Ninv; }
    const double var1 =
        s[6] - (sp[0] * sp[0] + sp[1] * sp[1] + sp[2] * sp[2]) * Ninv;

    double K[3][3];
#pragma unroll
    for (int i = 0; i < 3; ++i)
#pragma unroll
      for (int j = 0; j < 3; ++j)
        K[i][j] = s[7 + 3 * i + j] - sp[i] * sg[j] * Ninv + 1e-8;

    double A[3][3];
#pragma unroll
    for (int i = 0; i < 3; ++i)
#pragma unroll
      for (int j = 0; j < 3; ++j)
        A[i][j] = K[0][i] * K[0][j] + K[1][i] * K[1][j] + K[2][i] * K[2][j];

    double V[3][3] = {{1, 0, 0}, {0, 1, 0}, {0, 0, 1}};
    for (int sweep = 0; sweep < 30; ++sweep) {
      const double off =
          A[0][1] * A[0][1] + A[0][2] * A[0][2] + A[1][2] * A[1][2];
      const double nrm = A[0][0] + A[1][1] + A[2][2];
      if (off <= 1e-30 * nrm * nrm) break;
      JROT(0, 1, 2);
      JROT(0, 2, 1);
      JROT(1, 2, 0);
    }

    // sort eigenvalues descending, carrying V columns (constant indices only)
    double wv[3] = {A[0][0], A[1][1], A[2][2]};
    if (wv[0] < wv[1]) {
      double tw = wv[0]; wv[0] = wv[1]; wv[1] = tw;
#pragma unroll
      for (int k = 0; k < 3; ++k) {
        double tv = V[k][0]; V[k][0] = V[k][1]; V[k][1] = tv;
      }
    }
    if (wv[0] < wv[2]) {
      double tw = wv[0]; wv[0] = wv[2]; wv[2] = tw;
#pragma unroll
      for (int k = 0; k < 3; ++k) {
        double tv = V[k][0]; V[k][0] = V[k][2]; V[k][2] = tv;
      }
    }
    if (wv[1] < wv[2]) {
      double tw = wv[1]; wv[1] = wv[2]; wv[2] = tw;
#pragma unroll
      for (int k = 0; k < 3; ++k) {
        double tv = V[k][1]; V[k][1] = V[k][2]; V[k][2] = tv;
      }
    }
    const double sv0 = sqrt(fmax(wv[0], 0.0));
    const double sv1 = sqrt(fmax(wv[1], 0.0));
    const double sv2 = sqrt(fmax(wv[2], 0.0));

    const double detK =
        K[0][0] * (K[1][1] * K[2][2] - K[1][2] * K[2][1]) -
        K[0][1] * (K[1][0] * K[2][2] - K[1][2] * K[2][0]) +
        K[0][2] * (K[1][0] * K[2][1] - K[1][1] * K[2][0]);
    const double sgn = (detK > 0.0) ? 1.0 : ((detK < 0.0) ? -1.0 : 0.0);

    const double floor0 = sv0 * 1e-12 + 1e-300;
    const double z0 = 1.0 / fmax(sv0, floor0);
    const double z1 = 1.0 / fmax(sv1, floor0);
    const double z2 = sgn / fmax(sv2, floor0);

    double W[3][3];
#pragma unroll
    for (int a = 0; a < 3; ++a)
#pragma unroll
      for (int c = 0; c < 3; ++c)
        W[a][c] = V[a][0] * V[c][0] * z0 + V[a][1] * V[c][1] * z1 +
                  V[a][2] * V[c][2] * z2;

    double R[3][3];
#pragma unroll
    for (int a = 0; a < 3; ++a)
#pragma unroll
      for (int c = 0; c < 3; ++c)
        R[a][c] = W[a][0] * K[c][0] + W[a][1] * K[c][1] + W[a][2] * K[c][2];

    const double trace = sv0 + sv1 + sgn * sv2;
    const double scale = trace / var1;

#pragma unroll
    for (int a = 0; a < 3; ++a) {
#pragma unroll
      for (int c = 0; c < 3; ++c) pm[3 * a + c] = (float)(scale * R[a][c]);
      pm[9 + a] = (float)(mu2[a] - scale * (R[a][0] * mu1[0] +
                                            R[a][1] * mu1[1] +
                                            R[a][2] * mu1[2]));
    }
  }
  __syncthreads();

  // ---- Phase 3: apply; stage each chunk in LDS; contiguous nt-store ----
  float m[12];
#pragma unroll
  for (int i = 0; i < 12; ++i) m[i] = pm[i];

  // chunks k=0..2 (full: 1536 f4s each)
#pragma unroll
  for (int k = 0; k < 3; ++k) {
    f4 r0, r1, r2;
    apply_group(m, rp[k][0], rp[k][1], rp[k][2], rg[k][0], rg[k][1], rg[k][2],
                r0, r1, r2);
    stage[3 * t] = r0; stage[3 * t + 1] = r1; stage[3 * t + 2] = r2;
    __syncthreads();
#pragma unroll
    for (int j = 0; j < 3; ++j) {
      const int idx = t + NT * j;
      __builtin_nontemporal_store(stage[idx], &O[CHUNK_F4 * k + idx]);
    }
    __syncthreads();
  }
  // chunk 3 (partial: 186 groups = 558 f4s)
  if (has3) {
    f4 r0, r1, r2;
    apply_group(m, rp[3][0], rp[3][1], rp[3][2], rg[3][0], rg[3][1], rg[3][2],
                r0, r1, r2);
    stage[3 * t] = r0; stage[3 * t + 1] = r1; stage[3 * t + 2] = r2;
  }
  __syncthreads();
  {
    const int nrem = 3 * (NGROUPS - 3 * NT);         // 558
#pragma unroll
    for (int j = 0; j < 2; ++j) {
      const int idx = t + NT * j;
      if (idx < nrem)
        __builtin_nontemporal_store(stage[idx], &O[CHUNK_F4 * 3 + idx]);
    }
  }
  if (hasL) {
    const int n = skip ? t : (NPTS - 2 + t);
    float* oo = out + ofs0 + 3 * n;
    const F3 r = xform(m, lp0, lp1, lp2, lg0, lg1, lg2);
    oo[0] = r.x; oo[1] = r.y; oo[2] = r.z;
  }
}

extern "C" void kernel_launch(void* const* d_in, const int* in_sizes, int n_in,
                              void* d_out, int out_size, void* d_ws, size_t ws_size,
                              hipStream_t stream) {
  const float* pred = (const float*)d_in[0];
  const float* gt   = (const float*)d_in[1];
  float* out = (float*)d_out;
  hipLaunchKernelGGL(fused_kernel, dim3(BATCH), dim3(NT), 0, stream,
                     pred, gt, out);
}